// Round 3
// baseline (448.495 us; speedup 1.0000x reference)
//
#include <hip/hip_runtime.h>
#include <hip/hip_bf16.h>

#define DIMD 768
#define RNK  48
#define KADP 4
#define NB   8
#define NS   4096
#define NKR  192
#define GSTR 200          // g region row stride (bf16 elems); 100 dwords == 4 mod 32 banks
#define XSTR 776          // x_lds row stride (bf16 elems); 388 dwords == 4 mod 32 banks

typedef __attribute__((ext_vector_type(8))) short short8;
typedef __attribute__((ext_vector_type(4))) short short4v;
typedef __attribute__((ext_vector_type(4))) float floatx4;

__device__ __forceinline__ short f2bf(float f) {
    union { float f; unsigned u; } v; v.f = f;
    unsigned u = v.u;
    unsigned r = (u + 0x7fffu + ((u >> 16) & 1u)) >> 16;   // RNE
    return (short)(r & 0xffffu);
}

// ---------------------------------------------------------------------------
// ONE fused kernel. grid(128,8) = 1024 blocks = exactly 4 blocks/CU
// (LDS 24.8KB -> 6/CU cap, VGPR<=128 via launch_bounds(256,4), 16 waves/CU)
// => whole grid co-resident => device-scope rendezvous is safe.
//
// Flow per block (b = blockIdx.y, 32 tokens at s0):
//   [bx<18: pack its 256 weight frags; fence; atomicAdd(pack_done)]
//   stage rows 0..15 (full d, fp32->bf16 LDS) + fp32 pool partial per thread
//   wait pack_done==144                        (WdP ready)
//   phase-1 MFMAs for row-group 0 (24 kc)
//   stage rows 16..31 + pool partial; publish pool (atomicAdd) ; fence ;
//   arrive bcnt[b]                             (overlaps with next compute)
//   phase-1 MFMAs for row-group 1
//   wait bcnt[b]==128                          (pool[b] complete)
//   router softmax (redundant per block) ; biasb LDS table ; gelu epilogue -> g
//   phase-2 with SWAPPED operands: C[d][token] => float4 out stores
//
// MFMA 16x16x32 bf16 layouts (HW-verified):
//   A: lane holds A[m=lane&15][k=quad*8+j] ; B: B[k=quad*8+j][n=lane&15]
//   C: lane holds C[row=quad*4+reg][col=lane&15]
// A and B fragment lane-mappings are identical, so phase 2 uses the packed
// WuP frag as A (m=d) and the g frag as B (n=token): lane then holds 4
// consecutive d per token -> coalesced float4 stores.
// ---------------------------------------------------------------------------
__launch_bounds__(256, 4)
__global__ void adapter_fused(const float* __restrict__ x,
                              const float* __restrict__ Wd,
                              const float* __restrict__ bd,
                              const float* __restrict__ Wu,
                              const float* __restrict__ bu,
                              const float* __restrict__ Wr,
                              const float* __restrict__ br,
                              short* __restrict__ WdP, short* __restrict__ WuP,
                              float* __restrict__ pool, unsigned* __restrict__ sync,
                              float* __restrict__ out) {
    __shared__ short smem[16 * XSTR];          // 24832 B; g(12.8KB)+biasb(3KB) alias later
    __shared__ float wsh[16];
    const int tid = threadIdx.x;
    const int wave = tid >> 6, lane = tid & 63;
    const int col = lane & 15, quad = lane >> 4;
    const int bx = blockIdx.x, b = blockIdx.y;
    const int s0 = bx * 32;

    // ---- weight pack: 18 blocks per b (144 total) pack 256 frags each ----
    if (bx < 18) {
        int i = (b * 18 + bx) * 256 + tid;     // 0..36863
        if (i < 18432) {                       // Wd: 12 nt * 24 kc * 64 lanes
            int l = i & 63, tile = i >> 6;
            int kc = tile % 24, nt = tile / 24;
            int c = l & 15, q = l >> 4;
            int kr = nt * 16 + c;
            int k = kr / RNK, r = kr % RNK;
            short8 vals;
#pragma unroll
            for (int j = 0; j < 8; ++j) {
                int d = kc * 32 + q * 8 + j;
                vals[j] = f2bf(Wd[(k * DIMD + d) * RNK + r]);
            }
            *(short8*)(WdP + (size_t)i * 8) = vals;
        } else {                               // Wu: 48 nt * 6 kc * 64 lanes
            int i2 = i - 18432;
            int l = i2 & 63, tile = i2 >> 6;
            int kc = tile % 6, nt = tile / 6;
            int c = l & 15, q = l >> 4;
            int d = nt * 16 + c;
            short8 vals;
#pragma unroll
            for (int j = 0; j < 8; ++j) {
                int krk = kc * 32 + q * 8 + j;
                int k = krk / RNK, r = krk % RNK;
                vals[j] = f2bf(Wu[(k * RNK + r) * DIMD + d]);
            }
            *(short8*)(WuP + (size_t)i2 * 8) = vals;
        }
        __threadfence();                       // stores visible device-wide
        __syncthreads();
        if (tid == 0) atomicAdd(&sync[0], 1u);
    }

    // ---- stage row-group 0 (rows 0..15, full d) + pool partial ----
    float4 pacc = {0.f, 0.f, 0.f, 0.f};
    const float* xb = x + ((size_t)(b * NS + s0)) * DIMD;
    if (tid < 192) {
        const float* xr = xb + 4 * tid;
#pragma unroll 4
        for (int r = 0; r < 16; ++r) {
            float4 v = *(const float4*)(xr + (size_t)r * DIMD);
            pacc.x += v.x; pacc.y += v.y; pacc.z += v.z; pacc.w += v.w;
            short4v sv;
            sv[0] = f2bf(v.x); sv[1] = f2bf(v.y); sv[2] = f2bf(v.z); sv[3] = f2bf(v.w);
            *(short4v*)(smem + r * XSTR + 4 * tid) = sv;
        }
    }
    __syncthreads();

    // ---- wait: weights packed (producer flag, acquire) ----
    if (tid == 0) {
        while (__hip_atomic_load(&sync[0], __ATOMIC_ACQUIRE,
                                 __HIP_MEMORY_SCOPE_AGENT) < 144u)
            __builtin_amdgcn_s_sleep(2);
    }
    __syncthreads();

    // ---- phase 1, group 0 ----
    floatx4 acc[2][3];
#pragma unroll
    for (int g = 0; g < 2; ++g)
#pragma unroll
        for (int j = 0; j < 3; ++j) acc[g][j] = (floatx4){0.f, 0.f, 0.f, 0.f};

    const short* xl = smem + col * XSTR;
    const int ntb = wave * 3;
    for (int kc = 0; kc < 24; ++kc) {
        short8 a = *(const short8*)(xl + kc * 32 + quad * 8);
#pragma unroll
        for (int j = 0; j < 3; ++j) {
            short8 bf = *(const short8*)(WdP + ((size_t)((ntb + j) * 24 + kc) * 64 + lane) * 8);
            acc[0][j] = __builtin_amdgcn_mfma_f32_16x16x32_bf16(a, bf, acc[0][j], 0, 0, 0);
        }
    }
    __syncthreads();                           // group-0 reads done

    // ---- stage row-group 1 + pool partial ----
    if (tid < 192) {
        const float* xr = xb + (size_t)16 * DIMD + 4 * tid;
#pragma unroll 4
        for (int r = 0; r < 16; ++r) {
            float4 v = *(const float4*)(xr + (size_t)r * DIMD);
            pacc.x += v.x; pacc.y += v.y; pacc.z += v.z; pacc.w += v.w;
            short4v sv;
            sv[0] = f2bf(v.x); sv[1] = f2bf(v.y); sv[2] = f2bf(v.z); sv[3] = f2bf(v.w);
            *(short4v*)(smem + r * XSTR + 4 * tid) = sv;
        }
    }
    // publish pool partial (covers all 32 rows), then arrive at per-b barrier
    if (tid < 192) {
        atomicAdd(&pool[b * DIMD + 4 * tid + 0], pacc.x);
        atomicAdd(&pool[b * DIMD + 4 * tid + 1], pacc.y);
        atomicAdd(&pool[b * DIMD + 4 * tid + 2], pacc.z);
        atomicAdd(&pool[b * DIMD + 4 * tid + 3], pacc.w);
        __threadfence();                       // adds complete+visible
    }
    __syncthreads();                           // staging + adds done blockwide
    if (tid == 0) atomicAdd(&sync[1 + b], 1u);

    // ---- phase 1, group 1 (overlaps other blocks' arrivals) ----
    for (int kc = 0; kc < 24; ++kc) {
        short8 a = *(const short8*)(xl + kc * 32 + quad * 8);
#pragma unroll
        for (int j = 0; j < 3; ++j) {
            short8 bf = *(const short8*)(WdP + ((size_t)((ntb + j) * 24 + kc) * 64 + lane) * 8);
            acc[1][j] = __builtin_amdgcn_mfma_f32_16x16x32_bf16(a, bf, acc[1][j], 0, 0, 0);
        }
    }
    __syncthreads();                           // x_lds reads done (g will alias)

    // ---- wait: pool[b] complete (128 blocks of this b arrived) ----
    if (tid == 0) {
        while (__hip_atomic_load(&sync[1 + b], __ATOMIC_ACQUIRE,
                                 __HIP_MEMORY_SCOPE_AGENT) < 128u)
            __builtin_amdgcn_s_sleep(2);
    }
    __syncthreads();

    // ---- router: y[k] = dot(pool[b], Wr[:,k]) (redundant per block) ----
    {
        int k = tid & 3, dbase = tid >> 2;     // (k, dbase) unique over block
        float s = 0.f;
#pragma unroll
        for (int j = 0; j < 12; ++j) {
            int d = dbase + 64 * j;
            float pv = __hip_atomic_load(&pool[b * DIMD + d], __ATOMIC_RELAXED,
                                         __HIP_MEMORY_SCOPE_AGENT);
            s += pv * Wr[d * KADP + k];
        }
        s += __shfl_xor(s, 4); s += __shfl_xor(s, 8);
        s += __shfl_xor(s, 16); s += __shfl_xor(s, 32);
        if (lane < 4) wsh[wave * 4 + lane] = s;
    }
    __syncthreads();

    float y0 = (wsh[0] + wsh[4] + wsh[8] + wsh[12]) * (1.0f / NS) + br[0];
    float y1 = (wsh[1] + wsh[5] + wsh[9] + wsh[13]) * (1.0f / NS) + br[1];
    float y2 = (wsh[2] + wsh[6] + wsh[10] + wsh[14]) * (1.0f / NS) + br[2];
    float y3 = (wsh[3] + wsh[7] + wsh[11] + wsh[15]) * (1.0f / NS) + br[3];
    float mx = fmaxf(fmaxf(y0, y1), fmaxf(y2, y3));
    float e0 = __expf(y0 - mx), e1 = __expf(y1 - mx);
    float e2 = __expf(y2 - mx), e3 = __expf(y3 - mx);
    float inv = 1.0f / (e0 + e1 + e2 + e3);
    float w0 = e0 * inv, w1 = e1 * inv, w2 = e2 * inv, w3 = e3 * inv;

    // ---- biasb table: bbl[d] = sum_k w_k*bu[k][d]  (3KB LDS, after g rgn) ----
    float* bbl = (float*)(smem + 32 * GSTR);   // byte offset 12800, 16B aligned
#pragma unroll
    for (int d = tid; d < DIMD; d += 256)
        bbl[d] = w0 * bu[0 * DIMD + d] + w1 * bu[1 * DIMD + d]
               + w2 * bu[2 * DIMD + d] + w3 * bu[3 * DIMD + d];

    // ---- epilogue: +bd, tanh-GELU, *w_k, bf16 -> g region (C -> B layout) ----
#pragma unroll
    for (int g = 0; g < 2; ++g) {
#pragma unroll
        for (int j = 0; j < 3; ++j) {
            int kr = (ntb + j) * 16 + col;
            float bdv = bd[kr];
            int k = kr / RNK;
            float wk = (k == 0) ? w0 : (k == 1) ? w1 : (k == 2) ? w2 : w3;
#pragma unroll
            for (int reg = 0; reg < 4; ++reg) {
                float hh = acc[g][j][reg] + bdv;
                float zz = 0.7978845608028654f * (hh + 0.044715f * hh * hh * hh);
                float e = __expf(2.0f * zz);
                float th = 1.0f - 2.0f / (e + 1.0f);      // tanh(zz)
                float gv = 0.5f * hh * (1.0f + th) * wk;
                int row = g * 16 + quad * 4 + reg;
                smem[row * GSTR + kr] = f2bf(gv);
            }
        }
    }
    __syncthreads();

    // ---- phase 2: swapped operands -> C[d][token], float4 stores ----
    short8 ga[2][6];
#pragma unroll
    for (int mt = 0; mt < 2; ++mt)
#pragma unroll
        for (int kc = 0; kc < 6; ++kc)
            ga[mt][kc] = *(const short8*)(smem + (mt * 16 + col) * GSTR + kc * 32 + quad * 8);

    float* outw = out + ((size_t)(b * NS + s0)) * DIMD;
    const int ntb2 = wave * 12;
    for (int p = 0; p < 6; ++p) {
        int nt0 = ntb2 + p * 2, nt1 = nt0 + 1;
        floatx4 c00 = (floatx4){0.f, 0.f, 0.f, 0.f};   // [mt0][nt0]
        floatx4 c01 = (floatx4){0.f, 0.f, 0.f, 0.f};   // [mt0][nt1]
        floatx4 c10 = (floatx4){0.f, 0.f, 0.f, 0.f};   // [mt1][nt0]
        floatx4 c11 = (floatx4){0.f, 0.f, 0.f, 0.f};   // [mt1][nt1]
#pragma unroll
        for (int kc = 0; kc < 6; ++kc) {
            short8 wf0 = *(const short8*)(WuP + ((size_t)(nt0 * 6 + kc) * 64 + lane) * 8);
            short8 wf1 = *(const short8*)(WuP + ((size_t)(nt1 * 6 + kc) * 64 + lane) * 8);
            c00 = __builtin_amdgcn_mfma_f32_16x16x32_bf16(wf0, ga[0][kc], c00, 0, 0, 0);
            c10 = __builtin_amdgcn_mfma_f32_16x16x32_bf16(wf0, ga[1][kc], c10, 0, 0, 0);
            c01 = __builtin_amdgcn_mfma_f32_16x16x32_bf16(wf1, ga[0][kc], c01, 0, 0, 0);
            c11 = __builtin_amdgcn_mfma_f32_16x16x32_bf16(wf1, ga[1][kc], c11, 0, 0, 0);
        }
        float4 bb0 = *(const float4*)(bbl + nt0 * 16 + quad * 4);  // broadcast
        float4 bb1 = *(const float4*)(bbl + nt1 * 16 + quad * 4);
        size_t r0 = (size_t)col * DIMD;            // token row (group 0)
        size_t r1 = (size_t)(16 + col) * DIMD;     // token row (group 1)
        int d0 = nt0 * 16 + quad * 4, d1 = nt1 * 16 + quad * 4;
        float4 o;
        o.x = c00[0] + bb0.x; o.y = c00[1] + bb0.y; o.z = c00[2] + bb0.z; o.w = c00[3] + bb0.w;
        *(float4*)(outw + r0 + d0) = o;
        o.x = c10[0] + bb0.x; o.y = c10[1] + bb0.y; o.z = c10[2] + bb0.z; o.w = c10[3] + bb0.w;
        *(float4*)(outw + r1 + d0) = o;
        o.x = c01[0] + bb1.x; o.y = c01[1] + bb1.y; o.z = c01[2] + bb1.z; o.w = c01[3] + bb1.w;
        *(float4*)(outw + r0 + d1) = o;
        o.x = c11[0] + bb1.x; o.y = c11[1] + bb1.y; o.z = c11[2] + bb1.z; o.w = c11[3] + bb1.w;
        *(float4*)(outw + r1 + d1) = o;
    }
}

// ---------------------------------------------------------------------------
extern "C" void kernel_launch(void* const* d_in, const int* in_sizes, int n_in,
                              void* d_out, int out_size, void* d_ws, size_t ws_size,
                              hipStream_t stream) {
    const float* x  = (const float*)d_in[0];
    const float* Wd = (const float*)d_in[1];
    const float* bd = (const float*)d_in[2];
    const float* Wu = (const float*)d_in[3];
    const float* bu = (const float*)d_in[4];
    const float* Wr = (const float*)d_in[5];
    const float* br = (const float*)d_in[6];
    float* out = (float*)d_out;

    char* ws = (char*)d_ws;
    unsigned* syncw = (unsigned*)(ws);         // 16 u32 = 64 B
    float* pool = (float*)(ws + 64);           // 6144 f32 = 24576 B
    short* WdP  = (short*)(ws + 24640);        // 147456 bf16 = 294912 B
    short* WuP  = (short*)(ws + 319552);       // 147456 bf16 = 294912 B (total 614464)

    hipMemsetAsync(ws, 0, 24640, stream);      // sync counters + pool
    adapter_fused<<<dim3(128, 8), 256, 0, stream>>>(
        x, Wd, bd, Wu, bu, Wr, br, WdP, WuP, pool, syncw, out);
}

// Round 4
// 308.545 us; speedup vs baseline: 1.4536x; 1.4536x over previous
//
#include <hip/hip_runtime.h>
#include <hip/hip_bf16.h>

#define DIMD 768
#define RNK  48
#define KADP 4
#define NB   8
#define NS   4096
#define NKR  192
#define GSTR 200          // g region row stride (bf16); 100 dwords == 4 mod 32 banks
#define XSTR 776          // x_lds row stride (bf16); 388 dwords == 4 mod 32 banks

typedef __attribute__((ext_vector_type(8))) short short8;
typedef __attribute__((ext_vector_type(4))) short short4v;
typedef __attribute__((ext_vector_type(4))) float floatx4;

__device__ __forceinline__ short f2bf(float f) {
    union { float f; unsigned u; } v; v.f = f;
    unsigned u = v.u;
    unsigned r = (u + 0x7fffu + ((u >> 16) & 1u)) >> 16;   // RNE
    return (short)(r & 0xffffu);
}

// ---------------------------------------------------------------------------
// Prologue: 192-thread blocks (3 full waves, no idle lanes).
// blocks 0..2047: pool partials, 16 rows each, thread t owns d-chunk t*4
//   (192*4 = 768 exactly), 16 fully-unrolled independent float4 loads.
// blocks 2048..2239: weight pack (36864 frags / 192 = 192 blocks).
// pool must be zeroed by hipMemsetAsync before this kernel.
// Wd raw [k,d,r] -> down-B-frag: B[k=d][n=kr], kr=k*48+r
// Wu raw [k,r,d] -> up-B-frag:   B[k=kr][n=d]
// Packed addr (bf16): ((nt*KC + kc)*64 + lane)*8 + j ; k-in-chunk = quad*8+j
// ---------------------------------------------------------------------------
__launch_bounds__(192, 6)
__global__ void prologue(const float* __restrict__ x,
                         const float* __restrict__ Wd, const float* __restrict__ Wu,
                         short* __restrict__ WdP, short* __restrict__ WuP,
                         float* __restrict__ pool) {
    int blk = blockIdx.x;
    int tid = threadIdx.x;
    if (blk < 2048) {                     // ---- pool partial ----
        int b = blk >> 8, sc = blk & 255; // 16 s-rows per block
        const float* xp = x + ((size_t)(b * NS + sc * 16)) * DIMD + tid * 4;
        float4 acc = {0.f, 0.f, 0.f, 0.f};
#pragma unroll
        for (int s = 0; s < 16; ++s) {
            float4 v = *(const float4*)(xp + (size_t)s * DIMD);
            acc.x += v.x; acc.y += v.y; acc.z += v.z; acc.w += v.w;
        }
        atomicAdd(&pool[b * DIMD + tid * 4 + 0], acc.x);
        atomicAdd(&pool[b * DIMD + tid * 4 + 1], acc.y);
        atomicAdd(&pool[b * DIMD + tid * 4 + 2], acc.z);
        atomicAdd(&pool[b * DIMD + tid * 4 + 3], acc.w);
        return;
    }
    int i = (blk - 2048) * 192 + tid;     // ---- weight pack: i in [0,36864) ----
    if (i < 18432) {                      // Wd: 12 nt * 24 kc * 64 lanes
        int lane = i & 63, tile = i >> 6;
        int kc = tile % 24, nt = tile / 24;
        int col = lane & 15, quad = lane >> 4;
        int kr = nt * 16 + col;
        int k = kr / RNK, r = kr % RNK;
        short8 vals;
#pragma unroll
        for (int j = 0; j < 8; ++j) {
            int d = kc * 32 + quad * 8 + j;
            vals[j] = f2bf(Wd[(k * DIMD + d) * RNK + r]);
        }
        *(short8*)(WdP + (size_t)i * 8) = vals;
    } else {                              // Wu: 48 nt * 6 kc * 64 lanes
        int i2 = i - 18432;
        int lane = i2 & 63, tile = i2 >> 6;
        int kc = tile % 6, nt = tile / 6;
        int col = lane & 15, quad = lane >> 4;
        int d = nt * 16 + col;
        short8 vals;
#pragma unroll
        for (int j = 0; j < 8; ++j) {
            int krk = kc * 32 + quad * 8 + j;
            int k = krk / RNK, r = krk % RNK;
            vals[j] = f2bf(Wu[(k * RNK + r) * DIMD + d]);
        }
        *(short8*)(WuP + (size_t)i2 * 8) = vals;
    }
}

// ---------------------------------------------------------------------------
// Main: grid(256,8) = 2048 blocks, block 256 = 4 waves. Block owns 16 tokens
// (ONE m-tile). Occupancy redesign: smaller/more blocks pack CUs far better
// (measured occupancy was only ~8 waves/CU with 1024x32-token blocks);
// LDS 24.8KB -> 6 blocks/CU, launch_bounds(256,6) caps VGPR at 85.
// Wave w owns one n-quarter: phase 1 nt=3w..3w+2 (48 kr); phase 2 nt=12w..
// Router folded in (pool complete by stream order; redundant per block).
// MFMA 16x16x32 bf16 layouts (HW-verified):
//   A: lane holds A[m=lane&15][k=quad*8+j] ; B: B[k=quad*8+j][n=lane&15]
//   C: lane holds C[row=quad*4+reg][col=lane&15]
// ---------------------------------------------------------------------------
__launch_bounds__(256, 6)
__global__ void adapter_main(const float* __restrict__ x,
                             const float* __restrict__ bd,
                             const short* __restrict__ WdP,
                             const short* __restrict__ WuP,
                             const float* __restrict__ pool,
                             const float* __restrict__ Wr,
                             const float* __restrict__ br,
                             const float* __restrict__ bu,
                             float* __restrict__ out) {
    __shared__ short smem[16 * XSTR];          // 24832 B; g region aliases front
    __shared__ float wsh[16];                  // [wave][k] router partials
    const int tid = threadIdx.x;
    const int wave = tid >> 6, lane = tid & 63;
    const int col = lane & 15, quad = lane >> 4;
    const int b = blockIdx.y;
    const int s0 = blockIdx.x * 16;

    // ---- router partial: y[k] = dot(pool[b], Wr[:,k]) ----
    {
        int k = tid & 3, dbase = tid >> 2;     // thread covers d = dbase+64j
        float s = 0.f;
#pragma unroll
        for (int j = 0; j < 12; ++j) {
            int d = dbase + 64 * j;
            s += pool[b * DIMD + d] * Wr[d * KADP + k];
        }
        s += __shfl_xor(s, 4); s += __shfl_xor(s, 8);
        s += __shfl_xor(s, 16); s += __shfl_xor(s, 32);
        if (lane < 4) wsh[wave * 4 + lane] = s;   // lane==k for lanes 0..3
    }

    // ---- stage x tile [16 x 768] -> LDS bf16 (row-major, stride XSTR) ----
    const float* xb = x + ((size_t)(b * NS + s0)) * DIMD;
#pragma unroll 6
    for (int i = tid; i < 3072; i += 256) {    // 3072 float4 = 16*768 elems
        int row = i / 192, c = i % 192;
        float4 v = *(const float4*)(xb + (size_t)row * DIMD + c * 4);
        short4v sv;
        sv[0] = f2bf(v.x); sv[1] = f2bf(v.y); sv[2] = f2bf(v.z); sv[3] = f2bf(v.w);
        *(short4v*)(smem + row * XSTR + c * 4) = sv;
    }
    __syncthreads();

    // ---- Phase 1: h[16 x 48] (this wave's kr quarter) ----
    floatx4 acc[3];
#pragma unroll
    for (int j = 0; j < 3; ++j) acc[j] = (floatx4){0.f, 0.f, 0.f, 0.f};

    const short* xl = smem + col * XSTR;
    const int ntb = wave * 3;
    for (int kc = 0; kc < 24; ++kc) {
        short8 a = *(const short8*)(xl + kc * 32 + quad * 8);
#pragma unroll
        for (int j = 0; j < 3; ++j) {
            short8 bf = *(const short8*)(WdP + ((size_t)((ntb + j) * 24 + kc) * 64 + lane) * 8);
            acc[j] = __builtin_amdgcn_mfma_f32_16x16x32_bf16(a, bf, acc[j], 0, 0, 0);
        }
    }
    __syncthreads();    // all x_lds reads done before g overwrites the region

    // ---- router finish: softmax over 4 slots (redundant per thread) ----
    float y0 = (wsh[0] + wsh[4] + wsh[8] + wsh[12]) * (1.0f / NS) + br[0];
    float y1 = (wsh[1] + wsh[5] + wsh[9] + wsh[13]) * (1.0f / NS) + br[1];
    float y2 = (wsh[2] + wsh[6] + wsh[10] + wsh[14]) * (1.0f / NS) + br[2];
    float y3 = (wsh[3] + wsh[7] + wsh[11] + wsh[15]) * (1.0f / NS) + br[3];
    float mx = fmaxf(fmaxf(y0, y1), fmaxf(y2, y3));
    float e0 = __expf(y0 - mx), e1 = __expf(y1 - mx);
    float e2 = __expf(y2 - mx), e3 = __expf(y3 - mx);
    float inv = 1.0f / (e0 + e1 + e2 + e3);
    float w0 = e0 * inv, w1 = e1 * inv, w2 = e2 * inv, w3 = e3 * inv;

    // ---- epilogue: +bd, tanh-GELU, *w_k, bf16 -> g region (C -> A layout) ----
#pragma unroll
    for (int j = 0; j < 3; ++j) {
        int kr = (ntb + j) * 16 + col;
        float bdv = bd[kr];
        int k = kr / RNK;
        float wk = (k == 0) ? w0 : (k == 1) ? w1 : (k == 2) ? w2 : w3;
#pragma unroll
        for (int reg = 0; reg < 4; ++reg) {
            float hh = acc[j][reg] + bdv;
            float zz = 0.7978845608028654f * (hh + 0.044715f * hh * hh * hh);
            float e = __expf(2.0f * zz);
            float th = 1.0f - 2.0f / (e + 1.0f);      // tanh(zz)
            float g = 0.5f * hh * (1.0f + th) * wk;
            int row = quad * 4 + reg;
            smem[row * GSTR + kr] = f2bf(g);
        }
    }
    __syncthreads();

    // ---- Phase 2: out[16 x 192] (this wave's d quarter) ----
    short8 ga[6];
#pragma unroll
    for (int kc = 0; kc < 6; ++kc)
        ga[kc] = *(const short8*)(smem + col * GSTR + kc * 32 + quad * 8);

    float* outw = out + ((size_t)(b * NS + s0)) * DIMD;
    const int ntb2 = wave * 12;
    for (int p = 0; p < 6; ++p) {
        int nt = ntb2 + p * 2;
        floatx4 c0 = (floatx4){0.f, 0.f, 0.f, 0.f};
        floatx4 c1 = (floatx4){0.f, 0.f, 0.f, 0.f};
#pragma unroll
        for (int kc = 0; kc < 6; ++kc) {
            short8 b0 = *(const short8*)(WuP + ((size_t)((nt + 0) * 6 + kc) * 64 + lane) * 8);
            short8 b1 = *(const short8*)(WuP + ((size_t)((nt + 1) * 6 + kc) * 64 + lane) * 8);
            c0 = __builtin_amdgcn_mfma_f32_16x16x32_bf16(ga[kc], b0, c0, 0, 0, 0);
            c1 = __builtin_amdgcn_mfma_f32_16x16x32_bf16(ga[kc], b1, c1, 0, 0, 0);
        }
        int d0 = (nt + 0) * 16 + col, d1 = (nt + 1) * 16 + col;
        float bb0 = w0 * bu[0 * DIMD + d0] + w1 * bu[1 * DIMD + d0]
                  + w2 * bu[2 * DIMD + d0] + w3 * bu[3 * DIMD + d0];
        float bb1 = w0 * bu[0 * DIMD + d1] + w1 * bu[1 * DIMD + d1]
                  + w2 * bu[2 * DIMD + d1] + w3 * bu[3 * DIMD + d1];
#pragma unroll
        for (int reg = 0; reg < 4; ++reg) {
            int r0 = quad * 4 + reg;
            outw[(size_t)r0 * DIMD + d0] = c0[reg] + bb0;
            outw[(size_t)r0 * DIMD + d1] = c1[reg] + bb1;
        }
    }
}

// ---------------------------------------------------------------------------
extern "C" void kernel_launch(void* const* d_in, const int* in_sizes, int n_in,
                              void* d_out, int out_size, void* d_ws, size_t ws_size,
                              hipStream_t stream) {
    const float* x  = (const float*)d_in[0];
    const float* Wd = (const float*)d_in[1];
    const float* bd = (const float*)d_in[2];
    const float* Wu = (const float*)d_in[3];
    const float* bu = (const float*)d_in[4];
    const float* Wr = (const float*)d_in[5];
    const float* br = (const float*)d_in[6];
    float* out = (float*)d_out;

    char* ws = (char*)d_ws;
    float* pool = (float*)(ws);                // 6144 f32 = 24576 B
    short* WdP  = (short*)(ws + 24576);        // 147456 bf16 = 294912 B
    short* WuP  = (short*)(ws + 319488);       // 147456 bf16 = 294912 B (total 614400)

    hipMemsetAsync(pool, 0, NB * DIMD * sizeof(float), stream);
    prologue<<<2240, 192, 0, stream>>>(x, Wd, Wu, WdP, WuP, pool);
    adapter_main<<<dim3(256, 8), 256, 0, stream>>>(x, bd, WdP, WuP, pool, Wr, br, bu, out);
}

// Round 6
// 286.029 us; speedup vs baseline: 1.5680x; 1.0787x over previous
//
#include <hip/hip_runtime.h>
#include <hip/hip_bf16.h>

#define DIMD 768
#define RNK  48
#define KADP 4
#define NB   8
#define NS   4096
#define KRP  256          // padded kr: 4 adapters x 64 (48 data + 16 zero pad)
#define XSTR 392          // x_lds row stride (bf16): 384 data + 8 pad

typedef __attribute__((ext_vector_type(8))) short short8;
typedef __attribute__((ext_vector_type(4))) short short4v;
typedef __attribute__((ext_vector_type(4))) float floatx4;

__device__ __forceinline__ short f2bf(float f) {
    union { float f; unsigned u; } v; v.f = f;
    unsigned u = v.u;
    unsigned r = (u + 0x7fffu + ((u >> 16) & 1u)) >> 16;   // RNE
    return (short)(r & 0xffffu);
}

// ---------------------------------------------------------------------------
// pack: 192 blocks x 256.
//  i <  18432 : Wd frags (12 nt x 24 kc x 64 lanes)  B[k=d][n=kr], kr=k*48+r
//  i <  43008 : Wu frags PADDED (48 nt x 8 kc x 64)  B[k=kr_pad][n=d],
//               kr_pad = 64*adapter + r, rows r>=48 are ZERO (adapter-aligned
//               kc chunks let k2 scale per-adapter partials by w_k post-MFMA)
//  all threads: zero poolP[8][NB][768] (replay-safe, replaces memset dispatch)
// ---------------------------------------------------------------------------
__global__ void pack(const float* __restrict__ Wd, const float* __restrict__ Wu,
                     short* __restrict__ WdP, short* __restrict__ WuP,
                     float* __restrict__ poolP) {
    int i = blockIdx.x * 256 + threadIdx.x;
    if (i < 49152) poolP[i] = 0.f;             // 8*8*768
    if (i < 18432) {                           // Wd
        int lane = i & 63, tile = i >> 6;
        int kc = tile % 24, nt = tile / 24;
        int col = lane & 15, quad = lane >> 4;
        int kr = nt * 16 + col;
        int k = kr / RNK, r = kr % RNK;
        short8 vals;
#pragma unroll
        for (int j = 0; j < 8; ++j) {
            int d = kc * 32 + quad * 8 + j;
            vals[j] = f2bf(Wd[(k * DIMD + d) * RNK + r]);
        }
        *(short8*)(WdP + (size_t)i * 8) = vals;
    } else if (i < 43008) {                    // Wu padded
        int i2 = i - 18432;
        int lane = i2 & 63, tile = i2 >> 6;    // tile = nt*8 + kc
        int kc = tile & 7, nt = tile >> 3;
        int col = lane & 15, quad = lane >> 4;
        int d = nt * 16 + col;
        short8 vals;
#pragma unroll
        for (int j = 0; j < 8; ++j) {
            int krk = kc * 32 + quad * 8 + j;  // padded kr in [0,256)
            int k = krk >> 6, r = krk & 63;
            vals[j] = (r < RNK) ? f2bf(Wu[(k * RNK + r) * DIMD + d]) : (short)0;
        }
        *(short8*)(WuP + (size_t)i2 * 8) = vals;
    }
}

// ---------------------------------------------------------------------------
// k1: grid(128,8), 256 thr = 4 waves, 32 tokens/block, two-half d staging.
// Staging threads (t<192) own a FIXED 16B d-chunk per half -> fp32 pool
// accumulator in registers -> 4 atomicAdds into poolP slot (bx&7): only ~32
// serialized adds per address (contention was the round-4 prologue killer).
// Phase-1 MFMA (wave w owns adapter w's 48 kr), +bd, GELU (no w yet),
// bf16 -> g[b,s,kr_pad] global. Pad columns zero-filled (NaN-safe for k2).
// MFMA 16x16x32 bf16 (HW-verified): A: lane=A[m=lane&15][k=quad*8+j];
// B: B[k=quad*8+j][n=lane&15]; C: lane=C[row=quad*4+reg][col=lane&15]
// ---------------------------------------------------------------------------
__launch_bounds__(256, 6)
__global__ void k1_down(const float* __restrict__ x,
                        const float* __restrict__ bd,
                        const short* __restrict__ WdP,
                        float* __restrict__ poolP,
                        short* __restrict__ g) {
    __shared__ short smem[32 * XSTR];          // 25088 B
    const int tid = threadIdx.x;
    const int wave = tid >> 6, lane = tid & 63;
    const int col = lane & 15, quad = lane >> 4;
    const int b = blockIdx.y;
    const int s0 = blockIdx.x * 32;
    short* gb = g + ((size_t)(b * NS + s0)) * KRP;

    // zero the pad columns: 32 tokens x 4 adapters x 16 shorts; 16B/thread
    {
        int chunk = tid >> 1, off = (tid & 1) * 8;   // chunk: token*4+adapter
        int token = chunk >> 2, a = chunk & 3;
        short8 z = (short8){0,0,0,0,0,0,0,0};
        *(short8*)(gb + (size_t)token * KRP + a * 64 + RNK + off) = z;
    }

    const float* xb = x + ((size_t)(b * NS + s0)) * DIMD;
    floatx4 acc[2][3];
#pragma unroll
    for (int mt = 0; mt < 2; ++mt)
#pragma unroll
        for (int j = 0; j < 3; ++j) acc[mt][j] = (floatx4){0.f, 0.f, 0.f, 0.f};

    const short* xl0 = smem + col * XSTR;
    const short* xl1 = smem + (16 + col) * XSTR;
    const int slot = blockIdx.x & 7;

    for (int h = 0; h < 2; ++h) {
        if (h) __syncthreads();                // all reads of half 0 done
        if (tid < 192) {                       // stage + pool accumulate
            int chunk = tid % 96, rowg = tid / 96;   // 16 rows each
            const float* xp = xb + (size_t)(rowg * 16) * DIMD + h * 384 + chunk * 4;
            float4 pa = {0.f, 0.f, 0.f, 0.f};
#pragma unroll 4
            for (int r = 0; r < 16; ++r) {
                float4 v = *(const float4*)(xp + (size_t)r * DIMD);
                pa.x += v.x; pa.y += v.y; pa.z += v.z; pa.w += v.w;
                short4v sv;
                sv[0] = f2bf(v.x); sv[1] = f2bf(v.y); sv[2] = f2bf(v.z); sv[3] = f2bf(v.w);
                *(short4v*)(smem + (rowg * 16 + r) * XSTR + chunk * 4) = sv;
            }
            float* pp = poolP + ((size_t)slot * NB + b) * DIMD + h * 384 + chunk * 4;
            atomicAdd(pp + 0, pa.x); atomicAdd(pp + 1, pa.y);
            atomicAdd(pp + 2, pa.z); atomicAdd(pp + 3, pa.w);
        }
        __syncthreads();
        for (int kc = 0; kc < 12; ++kc) {
            short8 a0 = *(const short8*)(xl0 + kc * 32 + quad * 8);
            short8 a1 = *(const short8*)(xl1 + kc * 32 + quad * 8);
            int kcg = h * 12 + kc;
#pragma unroll
            for (int j = 0; j < 3; ++j) {
                short8 bf = *(const short8*)(WdP + ((size_t)((wave * 3 + j) * 24 + kcg) * 64 + lane) * 8);
                acc[0][j] = __builtin_amdgcn_mfma_f32_16x16x32_bf16(a0, bf, acc[0][j], 0, 0, 0);
                acc[1][j] = __builtin_amdgcn_mfma_f32_16x16x32_bf16(a1, bf, acc[1][j], 0, 0, 0);
            }
        }
    }

    // epilogue: +bd, tanh-GELU, bf16 -> g global. kr = wave*48 + j*16 + col
    // -> adapter = wave, kr_pad = wave*64 + j*16 + col.
#pragma unroll
    for (int mt = 0; mt < 2; ++mt) {
#pragma unroll
        for (int j = 0; j < 3; ++j) {
            float bdv = bd[wave * RNK + j * 16 + col];
#pragma unroll
            for (int reg = 0; reg < 4; ++reg) {
                float hh = acc[mt][j][reg] + bdv;
                float zz = 0.7978845608028654f * (hh + 0.044715f * hh * hh * hh);
                float e = __expf(2.0f * zz);
                float th = 1.0f - 2.0f / (e + 1.0f);      // tanh(zz)
                float gv = 0.5f * hh * (1.0f + th);
                int token = mt * 16 + quad * 4 + reg;
                gb[(size_t)token * KRP + wave * 64 + j * 16 + col] = f2bf(gv);
            }
        }
    }
}

// ---------------------------------------------------------------------------
// k2: grid(128,8) (same shape as k1 -> same block->XCD map -> g L2-local).
// Router from poolP (complete by stream order; redundant per block).
// Phase-2 with SWAPPED operands: A = WuP frag (m=d), B = g frag (n=token).
// kc chunks are adapter-aligned (padding) -> accumulate per-adapter partial
// (2 MFMAs), scale by w_k in fp32, sum. C: lane holds 4 consecutive d per
// token -> coalesced float4 out stores (16 tokens x 64B per instr).
// ---------------------------------------------------------------------------
__launch_bounds__(256, 4)
__global__ void k2_up(const short* __restrict__ g,
                      const short* __restrict__ WuP,
                      const float* __restrict__ poolP,
                      const float* __restrict__ Wr,
                      const float* __restrict__ br,
                      const float* __restrict__ bu,
                      float* __restrict__ out) {
    __shared__ float bbl[DIMD];                // w-weighted bu table
    __shared__ float wsh[16];
    const int tid = threadIdx.x;
    const int wave = tid >> 6, lane = tid & 63;
    const int col = lane & 15, quad = lane >> 4;
    const int b = blockIdx.y;
    const int s0 = blockIdx.x * 32;

    // ---- preload g fragments early (2 token-tiles x 8 kc) ----
    const short* gb = g + ((size_t)(b * NS + s0)) * KRP;
    short8 ga[2][8];
#pragma unroll
    for (int mt = 0; mt < 2; ++mt)
#pragma unroll
        for (int kc = 0; kc < 8; ++kc)
            ga[mt][kc] = *(const short8*)(gb + (size_t)(mt * 16 + col) * KRP + kc * 32 + quad * 8);

    // ---- router partial: y[k] = dot(pool[b], Wr[:,k]), pool = sum 8 slots ----
    {
        int k = tid & 3, dbase = tid >> 2;
        float s = 0.f;
#pragma unroll
        for (int j = 0; j < 12; ++j) {
            int d = dbase + 64 * j;
            float pv = 0.f;
#pragma unroll
            for (int p = 0; p < 8; ++p)
                pv += poolP[((size_t)p * NB + b) * DIMD + d];
            s += pv * Wr[d * KADP + k];
        }
        s += __shfl_xor(s, 4); s += __shfl_xor(s, 8);
        s += __shfl_xor(s, 16); s += __shfl_xor(s, 32);
        if (lane < 4) wsh[wave * 4 + lane] = s;
    }
    __syncthreads();

    float y0 = (wsh[0] + wsh[4] + wsh[8] + wsh[12]) * (1.0f / NS) + br[0];
    float y1 = (wsh[1] + wsh[5] + wsh[9] + wsh[13]) * (1.0f / NS) + br[1];
    float y2 = (wsh[2] + wsh[6] + wsh[10] + wsh[14]) * (1.0f / NS) + br[2];
    float y3 = (wsh[3] + wsh[7] + wsh[11] + wsh[15]) * (1.0f / NS) + br[3];
    float mx = fmaxf(fmaxf(y0, y1), fmaxf(y2, y3));
    float e0 = __expf(y0 - mx), e1 = __expf(y1 - mx);
    float e2 = __expf(y2 - mx), e3 = __expf(y3 - mx);
    float inv = 1.0f / (e0 + e1 + e2 + e3);
    float w0 = e0 * inv, w1 = e1 * inv, w2 = e2 * inv, w3 = e3 * inv;

    // bias table bbl[d] = sum_k w_k * bu[k][d]
#pragma unroll
    for (int d = tid; d < DIMD; d += 256)
        bbl[d] = w0 * bu[0 * DIMD + d] + w1 * bu[1 * DIMD + d]
               + w2 * bu[2 * DIMD + d] + w3 * bu[3 * DIMD + d];
    __syncthreads();

    const float wv[4] = {w0, w1, w2, w3};
    float* outw = out + ((size_t)(b * NS + s0)) * DIMD;

    // wave owns d in [wave*192, wave*192+192) = 12 m-tiles
#pragma unroll 2
    for (int p = 0; p < 12; ++p) {
        const int ntd = wave * 12 + p;         // d-tile index 0..47
        floatx4 ct0 = (floatx4){0.f, 0.f, 0.f, 0.f};
        floatx4 ct1 = (floatx4){0.f, 0.f, 0.f, 0.f};
#pragma unroll
        for (int k = 0; k < 4; ++k) {
            floatx4 a0 = (floatx4){0.f, 0.f, 0.f, 0.f};
            floatx4 a1 = (floatx4){0.f, 0.f, 0.f, 0.f};
#pragma unroll
            for (int kk = 0; kk < 2; ++kk) {
                int kc = k * 2 + kk;
                short8 wf = *(const short8*)(WuP + ((size_t)(ntd * 8 + kc) * 64 + lane) * 8);
                a0 = __builtin_amdgcn_mfma_f32_16x16x32_bf16(wf, ga[0][kc], a0, 0, 0, 0);
                a1 = __builtin_amdgcn_mfma_f32_16x16x32_bf16(wf, ga[1][kc], a1, 0, 0, 0);
            }
#pragma unroll
            for (int r = 0; r < 4; ++r) {
                ct0[r] += wv[k] * a0[r];
                ct1[r] += wv[k] * a1[r];
            }
        }
        int d0 = ntd * 16 + quad * 4;
        float4 bb = *(const float4*)(bbl + d0);
        float4 o;
        o.x = ct0[0] + bb.x; o.y = ct0[1] + bb.y; o.z = ct0[2] + bb.z; o.w = ct0[3] + bb.w;
        *(float4*)(outw + (size_t)col * DIMD + d0) = o;
        o.x = ct1[0] + bb.x; o.y = ct1[1] + bb.y; o.z = ct1[2] + bb.z; o.w = ct1[3] + bb.w;
        *(float4*)(outw + (size_t)(16 + col) * DIMD + d0) = o;
    }
}

// ---------------------------------------------------------------------------
extern "C" void kernel_launch(void* const* d_in, const int* in_sizes, int n_in,
                              void* d_out, int out_size, void* d_ws, size_t ws_size,
                              hipStream_t stream) {
    const float* x  = (const float*)d_in[0];
    const float* Wd = (const float*)d_in[1];
    const float* bd = (const float*)d_in[2];
    const float* Wu = (const float*)d_in[3];
    const float* bu = (const float*)d_in[4];
    const float* Wr = (const float*)d_in[5];
    const float* br = (const float*)d_in[6];
    float* out = (float*)d_out;

    char* ws = (char*)d_ws;
    float* poolP = (float*)(ws);               // 8*8*768 f32      = 196608 B
    short* WdP   = (short*)(ws + 196608);      // 18432*8  bf16    = 294912 B
    short* WuP   = (short*)(ws + 491520);      // 24576*8  bf16    = 393216 B
    short* g     = (short*)(ws + 884736);      // 8*4096*256 bf16  = 16777216 B

    pack<<<192, 256, 0, stream>>>(Wd, Wu, WdP, WuP, poolP);
    k1_down<<<dim3(128, 8), 256, 0, stream>>>(x, bd, WdP, poolP, g);
    k2_up<<<dim3(128, 8), 256, 0, stream>>>(g, WuP, poolP, Wr, br, bu, out);
}

// Round 7
// 239.802 us; speedup vs baseline: 1.8703x; 1.1928x over previous
//
#include <hip/hip_runtime.h>
#include <hip/hip_bf16.h>

#define DIMD 768
#define RNK  48
#define KADP 4
#define NB   8
#define NS   4096
#define NKR  192
#define GSTR 200          // g region row stride (bf16 elems)
#define XSTR 392          // x_lds row stride (bf16 elems): 384 data + 8 pad

typedef __attribute__((ext_vector_type(8))) short short8;
typedef __attribute__((ext_vector_type(4))) short short4v;
typedef __attribute__((ext_vector_type(4))) float floatx4;

__device__ __forceinline__ short f2bf(float f) {
    union { float f; unsigned u; } v; v.f = f;
    unsigned u = v.u;
    unsigned r = (u + 0x7fffu + ((u >> 16) & 1u)) >> 16;   // RNE
    return (short)(r & 0xffffu);
}

// ---------------------------------------------------------------------------
// Prologue: 192-thread blocks (3 full waves, no idle lanes).
// blocks 0..1023: pool partials, 32 s-rows each, thread t owns d-chunk t*4.
//   Register accumulate -> 4 atomicAdds into SLOT (blk&7): 16 contenders per
//   address instead of 128 (round-4 proved contention kills this pass;
//   round-6 k2 proved the slot-reduce in main is cheap).
// blocks 1024..1215: weight pack (36864 frags / 192 = 192 blocks).
// poolP must be zeroed by hipMemsetAsync before this kernel.
// Wd raw [k,d,r] -> down-B-frag: B[k=d][n=kr], kr=k*48+r
// Wu raw [k,r,d] -> up-B-frag:   B[k=kr][n=d]
// Packed addr (bf16): ((nt*KC + kc)*64 + lane)*8 + j ; k-in-chunk = quad*8+j
// ---------------------------------------------------------------------------
__launch_bounds__(192)
__global__ void prologue(const float* __restrict__ x,
                         const float* __restrict__ Wd, const float* __restrict__ Wu,
                         short* __restrict__ WdP, short* __restrict__ WuP,
                         float* __restrict__ poolP) {
    int blk = blockIdx.x;
    int tid = threadIdx.x;
    if (blk < 1024) {                     // ---- pool partial ----
        int b = blk >> 7, sc = blk & 127; // 32 s per block
        const float* xp = x + ((size_t)(b * NS + sc * 32)) * DIMD + tid * 4;
        float4 acc = {0.f, 0.f, 0.f, 0.f};
#pragma unroll 8
        for (int s = 0; s < 32; ++s) {
            float4 v = *(const float4*)(xp + (size_t)s * DIMD);
            acc.x += v.x; acc.y += v.y; acc.z += v.z; acc.w += v.w;
        }
        float* pp = poolP + ((size_t)(blk & 7) * NB + b) * DIMD + tid * 4;
        atomicAdd(pp + 0, acc.x);
        atomicAdd(pp + 1, acc.y);
        atomicAdd(pp + 2, acc.z);
        atomicAdd(pp + 3, acc.w);
        return;
    }
    int i = (blk - 1024) * 192 + tid;     // ---- weight pack: i in [0,36864) ----
    if (i < 18432) {                      // Wd: 12 nt * 24 kc * 64 lanes
        int lane = i & 63, tile = i >> 6;
        int kc = tile % 24, nt = tile / 24;
        int col = lane & 15, quad = lane >> 4;
        int kr = nt * 16 + col;
        int k = kr / RNK, r = kr % RNK;
        short8 vals;
#pragma unroll
        for (int j = 0; j < 8; ++j) {
            int d = kc * 32 + quad * 8 + j;
            vals[j] = f2bf(Wd[(k * DIMD + d) * RNK + r]);
        }
        *(short8*)(WdP + (size_t)i * 8) = vals;
    } else {                              // Wu: 48 nt * 6 kc * 64 lanes
        int i2 = i - 18432;
        int lane = i2 & 63, tile = i2 >> 6;
        int kc = tile % 6, nt = tile / 6;
        int col = lane & 15, quad = lane >> 4;
        int d = nt * 16 + col;
        short8 vals;
#pragma unroll
        for (int j = 0; j < 8; ++j) {
            int krk = kc * 32 + quad * 8 + j;
            int k = krk / RNK, r = krk % RNK;
            vals[j] = f2bf(Wu[(k * RNK + r) * DIMD + d]);
        }
        *(short8*)(WuP + (size_t)i2 * 8) = vals;
    }
}

// ---------------------------------------------------------------------------
// Main: round-1 structure verbatim (best measured, 67 µs invariant across 5
// variants) with two evidence-backed tweaks: router reads the 8-slot pool
// (round-6-k2-proven) and PLAIN out stores (round-0-proven: NT stores
// inflated WRITE_SIZE 98->111 MB).
// grid(128,8), block 256 = 4 waves. Block owns 32 tokens (2 m-tiles),
// x staged in two k-halves (32 x 384 bf16, stride 392 -> 25.1KB LDS).
// Wave w: phase 1 nt=3w..3w+2 (48 kr); phase 2 nt=12w..12w+11 (192 d).
// MFMA 16x16x32 bf16 layouts (HW-verified):
//   A: lane holds A[m=lane&15][k=quad*8+j] ; B: B[k=quad*8+j][n=lane&15]
//   C: lane holds C[row=quad*4+reg][col=lane&15]
// ---------------------------------------------------------------------------
__launch_bounds__(256, 4)
__global__ void adapter_main(const float* __restrict__ x,
                             const float* __restrict__ bd,
                             const short* __restrict__ WdP,
                             const short* __restrict__ WuP,
                             const float* __restrict__ poolP,
                             const float* __restrict__ Wr,
                             const float* __restrict__ br,
                             const float* __restrict__ bu,
                             float* __restrict__ out) {
    __shared__ short smem[32 * XSTR];          // 25088 B; g region aliases front
    __shared__ float wsh[16];                  // [wave][k] router partials
    const int tid = threadIdx.x;
    const int wave = tid >> 6, lane = tid & 63;
    const int col = lane & 15, quad = lane >> 4;
    const int b = blockIdx.y;
    const int s0 = blockIdx.x * 32;

    // ---- router partial: y[k] = dot(pool[b], Wr[:,k]); pool = sum 8 slots ----
    {
        int k = tid & 3, dbase = tid >> 2;     // thread covers d = dbase+64j
        float s = 0.f;
#pragma unroll
        for (int j = 0; j < 12; ++j) {
            int d = dbase + 64 * j;
            float pv = 0.f;
#pragma unroll
            for (int p = 0; p < 8; ++p)
                pv += poolP[((size_t)p * NB + b) * DIMD + d];
            s += pv * Wr[d * KADP + k];
        }
        s += __shfl_xor(s, 4); s += __shfl_xor(s, 8);
        s += __shfl_xor(s, 16); s += __shfl_xor(s, 32);
        if (lane < 4) wsh[wave * 4 + lane] = s;   // lane==k for lanes 0..3
    }

    // ---- Phase 1: h[32 x 48] (this wave's kr quarter), k-split staging ----
    const float* xbp = x + ((size_t)(b * NS + s0)) * DIMD;
    floatx4 acc[2][3];
#pragma unroll
    for (int mt = 0; mt < 2; ++mt)
#pragma unroll
        for (int j = 0; j < 3; ++j) acc[mt][j] = (floatx4){0.f, 0.f, 0.f, 0.f};

    const short* xl0 = smem + col * XSTR;
    const short* xl1 = smem + (16 + col) * XSTR;
    const int ntb = wave * 3;

    for (int h = 0; h < 2; ++h) {
        if (h) __syncthreads();                // all reads of half h-1 done
        // stage x half h: [32 rows x 384 floats] -> bf16 LDS
#pragma unroll 6
        for (int i = tid; i < 3072; i += 256) {   // 3072 float4
            int row = i / 96, c = i % 96;
            float4 v = *(const float4*)(xbp + (size_t)row * DIMD + h * 384 + c * 4);
            short4v sv;
            sv[0] = f2bf(v.x); sv[1] = f2bf(v.y); sv[2] = f2bf(v.z); sv[3] = f2bf(v.w);
            *(short4v*)(smem + row * XSTR + c * 4) = sv;
        }
        __syncthreads();
        for (int kc = 0; kc < 12; ++kc) {
            short8 a0 = *(const short8*)(xl0 + kc * 32 + quad * 8);
            short8 a1 = *(const short8*)(xl1 + kc * 32 + quad * 8);
            int kcg = h * 12 + kc;
#pragma unroll
            for (int j = 0; j < 3; ++j) {
                short8 bf = *(const short8*)(WdP + ((size_t)((ntb + j) * 24 + kcg) * 64 + lane) * 8);
                acc[0][j] = __builtin_amdgcn_mfma_f32_16x16x32_bf16(a0, bf, acc[0][j], 0, 0, 0);
                acc[1][j] = __builtin_amdgcn_mfma_f32_16x16x32_bf16(a1, bf, acc[1][j], 0, 0, 0);
            }
        }
    }
    __syncthreads();    // all x_lds reads done before g overwrites the region

    // ---- router finish: softmax over 4 slots (redundant per thread) ----
    float y0 = (wsh[0] + wsh[4] + wsh[8] + wsh[12]) * (1.0f / NS) + br[0];
    float y1 = (wsh[1] + wsh[5] + wsh[9] + wsh[13]) * (1.0f / NS) + br[1];
    float y2 = (wsh[2] + wsh[6] + wsh[10] + wsh[14]) * (1.0f / NS) + br[2];
    float y3 = (wsh[3] + wsh[7] + wsh[11] + wsh[15]) * (1.0f / NS) + br[3];
    float mx = fmaxf(fmaxf(y0, y1), fmaxf(y2, y3));
    float e0 = __expf(y0 - mx), e1 = __expf(y1 - mx);
    float e2 = __expf(y2 - mx), e3 = __expf(y3 - mx);
    float inv = 1.0f / (e0 + e1 + e2 + e3);
    float w0 = e0 * inv, w1 = e1 * inv, w2 = e2 * inv, w3 = e3 * inv;

    // ---- epilogue: +bd, tanh-GELU, *w_k, bf16 -> g region (C -> A layout) ----
#pragma unroll
    for (int mt = 0; mt < 2; ++mt) {
#pragma unroll
        for (int j = 0; j < 3; ++j) {
            int kr = (ntb + j) * 16 + col;
            float bdv = bd[kr];
            int k = kr / RNK;
            float wk = (k == 0) ? w0 : (k == 1) ? w1 : (k == 2) ? w2 : w3;
#pragma unroll
            for (int reg = 0; reg < 4; ++reg) {
                float hh = acc[mt][j][reg] + bdv;
                float zz = 0.7978845608028654f * (hh + 0.044715f * hh * hh * hh);
                float e = __expf(2.0f * zz);
                float th = 1.0f - 2.0f / (e + 1.0f);      // tanh(zz)
                float g = 0.5f * hh * (1.0f + th) * wk;
                int row = mt * 16 + quad * 4 + reg;
                smem[row * GSTR + kr] = f2bf(g);
            }
        }
    }
    __syncthreads();

    // ---- Phase 2: out[32 x 192] (this wave's d quarter), two m-tile passes ----
    float* outw = out + ((size_t)(b * NS + s0)) * DIMD;
    const int ntb2 = wave * 12;
#pragma unroll 1
    for (int mt = 0; mt < 2; ++mt) {
        short8 ga[6];
#pragma unroll
        for (int kc = 0; kc < 6; ++kc)
            ga[kc] = *(const short8*)(smem + (mt * 16 + col) * GSTR + kc * 32 + quad * 8);
        for (int p = 0; p < 6; ++p) {
            int nt = ntb2 + p * 2;
            floatx4 c0 = (floatx4){0.f, 0.f, 0.f, 0.f};
            floatx4 c1 = (floatx4){0.f, 0.f, 0.f, 0.f};
#pragma unroll
            for (int kc = 0; kc < 6; ++kc) {
                short8 b0 = *(const short8*)(WuP + ((size_t)((nt + 0) * 6 + kc) * 64 + lane) * 8);
                short8 b1 = *(const short8*)(WuP + ((size_t)((nt + 1) * 6 + kc) * 64 + lane) * 8);
                c0 = __builtin_amdgcn_mfma_f32_16x16x32_bf16(ga[kc], b0, c0, 0, 0, 0);
                c1 = __builtin_amdgcn_mfma_f32_16x16x32_bf16(ga[kc], b1, c1, 0, 0, 0);
            }
            int d0 = (nt + 0) * 16 + col, d1 = (nt + 1) * 16 + col;
            float bb0 = w0 * bu[0 * DIMD + d0] + w1 * bu[1 * DIMD + d0]
                      + w2 * bu[2 * DIMD + d0] + w3 * bu[3 * DIMD + d0];
            float bb1 = w0 * bu[0 * DIMD + d1] + w1 * bu[1 * DIMD + d1]
                      + w2 * bu[2 * DIMD + d1] + w3 * bu[3 * DIMD + d1];
#pragma unroll
            for (int reg = 0; reg < 4; ++reg) {
                int r0 = mt * 16 + quad * 4 + reg;
                outw[(size_t)r0 * DIMD + d0] = c0[reg] + bb0;
                outw[(size_t)r0 * DIMD + d1] = c1[reg] + bb1;
            }
        }
    }
}

// ---------------------------------------------------------------------------
extern "C" void kernel_launch(void* const* d_in, const int* in_sizes, int n_in,
                              void* d_out, int out_size, void* d_ws, size_t ws_size,
                              hipStream_t stream) {
    const float* x  = (const float*)d_in[0];
    const float* Wd = (const float*)d_in[1];
    const float* bd = (const float*)d_in[2];
    const float* Wu = (const float*)d_in[3];
    const float* bu = (const float*)d_in[4];
    const float* Wr = (const float*)d_in[5];
    const float* br = (const float*)d_in[6];
    float* out = (float*)d_out;

    char* ws = (char*)d_ws;
    float* poolP = (float*)(ws);               // 8 slots * 8 * 768 f32 = 196608 B
    short* WdP   = (short*)(ws + 196608);      // 147456 bf16 = 294912 B
    short* WuP   = (short*)(ws + 491520);      // 147456 bf16 = 294912 B (total 786432)

    hipMemsetAsync(poolP, 0, 196608, stream);
    prologue<<<1216, 192, 0, stream>>>(x, Wd, Wu, WdP, WuP, poolP);
    adapter_main<<<dim3(128, 8), 256, 0, stream>>>(x, bd, WdP, WuP, poolP, Wr, br, bu, out);
}

// Round 8
// 233.626 us; speedup vs baseline: 1.9197x; 1.0264x over previous
//
#include <hip/hip_runtime.h>
#include <hip/hip_bf16.h>

#define DIMD 768
#define RNK  48
#define KADP 4
#define NB   8
#define NS   4096
#define NSLOT 16          // pool contention-spreading slots
#define QSTR 200          // quarter-buffer row stride (bf16); 100 dwords == 4 mod 32
#define QBUF 6400         // shorts per quarter buffer (32 rows x 200)
#define GSTR 200          // g region stride == QSTR (g aliases buf0)

typedef __attribute__((ext_vector_type(8))) short short8;
typedef __attribute__((ext_vector_type(4))) short short4v;
typedef __attribute__((ext_vector_type(4))) float floatx4;

__device__ __forceinline__ short f2bf(float f) {
    union { float f; unsigned u; } v; v.f = f;
    unsigned u = v.u;
    unsigned r = (u + 0x7fffu + ((u >> 16) & 1u)) >> 16;   // RNE
    return (short)(r & 0xffffu);
}

// ---------------------------------------------------------------------------
// Prologue: 192-thread blocks.
// blocks 0..2047: pool partials, 16 s-rows each, thread t owns d-chunk t*4.
//   Register accumulate -> 4 atomicAdds into slot (blk&15): 16 contenders per
//   address (round-4 isolated contention as the killer; round-7 proved 16-way
//   is fine). 2x blocks vs round 7 = better load-latency hiding.
// blocks 2048..2239: weight pack (36864 frags / 192 = 192 blocks).
// poolP must be zeroed by hipMemsetAsync before this kernel.
// Wd raw [k,d,r] -> down-B-frag: B[k=d][n=kr], kr=k*48+r
// Wu raw [k,r,d] -> up-B-frag:   B[k=kr][n=d]
// Packed addr (bf16): ((nt*KC + kc)*64 + lane)*8 + j ; k-in-chunk = quad*8+j
// ---------------------------------------------------------------------------
__launch_bounds__(192)
__global__ void prologue(const float* __restrict__ x,
                         const float* __restrict__ Wd, const float* __restrict__ Wu,
                         short* __restrict__ WdP, short* __restrict__ WuP,
                         float* __restrict__ poolP) {
    int blk = blockIdx.x;
    int tid = threadIdx.x;
    if (blk < 2048) {                     // ---- pool partial ----
        int b = blk >> 8, sc = blk & 255; // 16 s per block
        const float* xp = x + ((size_t)(b * NS + sc * 16)) * DIMD + tid * 4;
        float4 acc = {0.f, 0.f, 0.f, 0.f};
#pragma unroll
        for (int s = 0; s < 16; ++s) {
            float4 v = *(const float4*)(xp + (size_t)s * DIMD);
            acc.x += v.x; acc.y += v.y; acc.z += v.z; acc.w += v.w;
        }
        float* pp = poolP + ((size_t)(blk & 15) * NB + b) * DIMD + tid * 4;
        atomicAdd(pp + 0, acc.x);
        atomicAdd(pp + 1, acc.y);
        atomicAdd(pp + 2, acc.z);
        atomicAdd(pp + 3, acc.w);
        return;
    }
    int i = (blk - 2048) * 192 + tid;     // ---- weight pack: i in [0,36864) ----
    if (i < 18432) {                      // Wd: 12 nt * 24 kc * 64 lanes
        int lane = i & 63, tile = i >> 6;
        int kc = tile % 24, nt = tile / 24;
        int col = lane & 15, quad = lane >> 4;
        int kr = nt * 16 + col;
        int k = kr / RNK, r = kr % RNK;
        short8 vals;
#pragma unroll
        for (int j = 0; j < 8; ++j) {
            int d = kc * 32 + quad * 8 + j;
            vals[j] = f2bf(Wd[(k * DIMD + d) * RNK + r]);
        }
        *(short8*)(WdP + (size_t)i * 8) = vals;
    } else {                              // Wu: 48 nt * 6 kc * 64 lanes
        int i2 = i - 18432;
        int lane = i2 & 63, tile = i2 >> 6;
        int kc = tile % 6, nt = tile / 6;
        int col = lane & 15, quad = lane >> 4;
        int d = nt * 16 + col;
        short8 vals;
#pragma unroll
        for (int j = 0; j < 8; ++j) {
            int krk = kc * 32 + quad * 8 + j;
            int k = krk / RNK, r = krk % RNK;
            vals[j] = f2bf(Wu[(k * RNK + r) * DIMD + d]);
        }
        *(short8*)(WuP + (size_t)i2 * 8) = vals;
    }
}

// ---------------------------------------------------------------------------
// Main: grid(128,8), block 256 = 4 waves, 32 tokens/block.
// PIPELINED phase 1 (the round-8 change): K split into 4 quarters (192 each),
// two 12.8KB LDS quarter-buffers. Per quarter q:
//   issue global loads of quarter q+1 into regs (pf[6])   <- before barrier!
//   __syncthreads()                                       <- one barrier/quarter
//   MFMA on buf[q&1]
//   cvt+ds_write pf -> buf[(q+1)&1]  (safe: that buffer's last readers
//                                     finished before the PREVIOUS barrier)
// Loads stream continuously instead of bursting between barriers — this
// attacks the measured 28% HBM duty cycle that 6 structural variants shared.
// Epilogue g (12.8KB, stride QSTR) aliases buf0: last MFMA reads buf1, so no
// extra barrier before g writes. Phase 2 single-pass ga[2][6] (VGPR headroom).
// MFMA 16x16x32 bf16 layouts (HW-verified):
//   A: lane holds A[m=lane&15][k=quad*8+j] ; B: B[k=quad*8+j][n=lane&15]
//   C: lane holds C[row=quad*4+reg][col=lane&15]
// ---------------------------------------------------------------------------
__launch_bounds__(256, 4)
__global__ void adapter_main(const float* __restrict__ x,
                             const float* __restrict__ bd,
                             const short* __restrict__ WdP,
                             const short* __restrict__ WuP,
                             const float* __restrict__ poolP,
                             const float* __restrict__ Wr,
                             const float* __restrict__ br,
                             const float* __restrict__ bu,
                             float* __restrict__ out) {
    __shared__ short smem[2 * QBUF];           // 25600 B; g region aliases buf0
    __shared__ float wsh[16];                  // [wave][k] router partials
    const int tid = threadIdx.x;
    const int wave = tid >> 6, lane = tid & 63;
    const int col = lane & 15, quad = lane >> 4;
    const int b = blockIdx.y;
    const int s0 = blockIdx.x * 32;

    // ---- router partial: y[k] = dot(pool[b], Wr[:,k]); pool = sum 16 slots ----
    {
        int k = tid & 3, dbase = tid >> 2;     // thread covers d = dbase+64j
        float s = 0.f;
#pragma unroll
        for (int j = 0; j < 12; ++j) {
            int d = dbase + 64 * j;
            float pv = 0.f;
#pragma unroll
            for (int p = 0; p < NSLOT; ++p)
                pv += poolP[((size_t)p * NB + b) * DIMD + d];
            s += pv * Wr[d * KADP + k];
        }
        s += __shfl_xor(s, 4); s += __shfl_xor(s, 8);
        s += __shfl_xor(s, 16); s += __shfl_xor(s, 32);
        if (lane < 4) wsh[wave * 4 + lane] = s;   // lane==k for lanes 0..3
    }

    // ---- per-thread staging geometry (constant across quarters) ----
    int rw[6], cc[6];
#pragma unroll
    for (int t = 0; t < 6; ++t) {
        int i = tid + t * 256;                 // 1536 float4 per quarter
        rw[t] = i / 48; cc[t] = (i % 48) * 4;  // row 0..31, float col 0..188
    }
    const float* xbp = x + ((size_t)(b * NS + s0)) * DIMD;

    floatx4 acc[2][3];
#pragma unroll
    for (int mt = 0; mt < 2; ++mt)
#pragma unroll
        for (int j = 0; j < 3; ++j) acc[mt][j] = (floatx4){0.f, 0.f, 0.f, 0.f};

    const int ntb = wave * 3;
    float4 pf[6];

    // ---- preload quarter 0 ----
#pragma unroll
    for (int t = 0; t < 6; ++t)
        pf[t] = *(const float4*)(xbp + (size_t)rw[t] * DIMD + cc[t]);
#pragma unroll
    for (int t = 0; t < 6; ++t) {
        short4v sv;
        sv[0] = f2bf(pf[t].x); sv[1] = f2bf(pf[t].y);
        sv[2] = f2bf(pf[t].z); sv[3] = f2bf(pf[t].w);
        *(short4v*)(smem + rw[t] * QSTR + cc[t]) = sv;
    }

    // ---- pipelined quarters ----
#pragma unroll
    for (int q = 0; q < 4; ++q) {
        if (q < 3) {                           // issue loads for q+1 (fly over barrier+MFMA)
#pragma unroll
            for (int t = 0; t < 6; ++t)
                pf[t] = *(const float4*)(xbp + (size_t)rw[t] * DIMD + (q + 1) * 192 + cc[t]);
        }
        __syncthreads();                       // buf[q&1] writes visible; prev readers done
        const short* xq = smem + (q & 1) * QBUF;
        const short* xl0 = xq + col * QSTR;
        const short* xl1 = xq + (16 + col) * QSTR;
#pragma unroll
        for (int kc = 0; kc < 6; ++kc) {
            short8 a0 = *(const short8*)(xl0 + kc * 32 + quad * 8);
            short8 a1 = *(const short8*)(xl1 + kc * 32 + quad * 8);
            int kcg = q * 6 + kc;
#pragma unroll
            for (int j = 0; j < 3; ++j) {
                short8 bf = *(const short8*)(WdP + ((size_t)((ntb + j) * 24 + kcg) * 64 + lane) * 8);
                acc[0][j] = __builtin_amdgcn_mfma_f32_16x16x32_bf16(a0, bf, acc[0][j], 0, 0, 0);
                acc[1][j] = __builtin_amdgcn_mfma_f32_16x16x32_bf16(a1, bf, acc[1][j], 0, 0, 0);
            }
        }
        if (q < 3) {                           // write q+1 into the other buffer
            short* dst = smem + ((q + 1) & 1) * QBUF;
#pragma unroll
            for (int t = 0; t < 6; ++t) {
                short4v sv;
                sv[0] = f2bf(pf[t].x); sv[1] = f2bf(pf[t].y);
                sv[2] = f2bf(pf[t].z); sv[3] = f2bf(pf[t].w);
                *(short4v*)(dst + rw[t] * QSTR + cc[t]) = sv;
            }
        }
    }

    // ---- router finish: softmax over 4 slots (redundant per thread) ----
    float y0 = (wsh[0] + wsh[4] + wsh[8] + wsh[12]) * (1.0f / NS) + br[0];
    float y1 = (wsh[1] + wsh[5] + wsh[9] + wsh[13]) * (1.0f / NS) + br[1];
    float y2 = (wsh[2] + wsh[6] + wsh[10] + wsh[14]) * (1.0f / NS) + br[2];
    float y3 = (wsh[3] + wsh[7] + wsh[11] + wsh[15]) * (1.0f / NS) + br[3];
    float mx = fmaxf(fmaxf(y0, y1), fmaxf(y2, y3));
    float e0 = __expf(y0 - mx), e1 = __expf(y1 - mx);
    float e2 = __expf(y2 - mx), e3 = __expf(y3 - mx);
    float inv = 1.0f / (e0 + e1 + e2 + e3);
    float w0 = e0 * inv, w1 = e1 * inv, w2 = e2 * inv, w3 = e3 * inv;

    // ---- epilogue: +bd, tanh-GELU, *w_k, bf16 -> g region (aliases buf0).
    //      Last MFMA read buf1; buf0's readers finished before q3's barrier,
    //      so no extra barrier needed before these writes. ----
#pragma unroll
    for (int mt = 0; mt < 2; ++mt) {
#pragma unroll
        for (int j = 0; j < 3; ++j) {
            int kr = (ntb + j) * 16 + col;
            float bdv = bd[kr];
            int k = kr / RNK;
            float wk = (k == 0) ? w0 : (k == 1) ? w1 : (k == 2) ? w2 : w3;
#pragma unroll
            for (int reg = 0; reg < 4; ++reg) {
                float hh = acc[mt][j][reg] + bdv;
                float zz = 0.7978845608028654f * (hh + 0.044715f * hh * hh * hh);
                float e = __expf(2.0f * zz);
                float th = 1.0f - 2.0f / (e + 1.0f);      // tanh(zz)
                float g = 0.5f * hh * (1.0f + th) * wk;
                int row = mt * 16 + quad * 4 + reg;
                smem[row * GSTR + kr] = f2bf(g);
            }
        }
    }
    __syncthreads();

    // ---- Phase 2: out[32 x 192] (this wave's d quarter), single pass ----
    short8 ga[2][6];
#pragma unroll
    for (int mt = 0; mt < 2; ++mt)
#pragma unroll
        for (int kc = 0; kc < 6; ++kc)
            ga[mt][kc] = *(const short8*)(smem + (mt * 16 + col) * GSTR + kc * 32 + quad * 8);

    float* outw = out + ((size_t)(b * NS + s0)) * DIMD;
    const int ntb2 = wave * 12;
    for (int p = 0; p < 6; ++p) {
        int nt = ntb2 + p * 2;
        floatx4 c00 = (floatx4){0.f, 0.f, 0.f, 0.f};
        floatx4 c01 = (floatx4){0.f, 0.f, 0.f, 0.f};
        floatx4 c10 = (floatx4){0.f, 0.f, 0.f, 0.f};
        floatx4 c11 = (floatx4){0.f, 0.f, 0.f, 0.f};
#pragma unroll
        for (int kc = 0; kc < 6; ++kc) {
            short8 b0 = *(const short8*)(WuP + ((size_t)((nt + 0) * 6 + kc) * 64 + lane) * 8);
            short8 b1 = *(const short8*)(WuP + ((size_t)((nt + 1) * 6 + kc) * 64 + lane) * 8);
            c00 = __builtin_amdgcn_mfma_f32_16x16x32_bf16(ga[0][kc], b0, c00, 0, 0, 0);
            c01 = __builtin_amdgcn_mfma_f32_16x16x32_bf16(ga[0][kc], b1, c01, 0, 0, 0);
            c10 = __builtin_amdgcn_mfma_f32_16x16x32_bf16(ga[1][kc], b0, c10, 0, 0, 0);
            c11 = __builtin_amdgcn_mfma_f32_16x16x32_bf16(ga[1][kc], b1, c11, 0, 0, 0);
        }
        int d0 = (nt + 0) * 16 + col, d1 = (nt + 1) * 16 + col;
        float bb0 = w0 * bu[0 * DIMD + d0] + w1 * bu[1 * DIMD + d0]
                  + w2 * bu[2 * DIMD + d0] + w3 * bu[3 * DIMD + d0];
        float bb1 = w0 * bu[0 * DIMD + d1] + w1 * bu[1 * DIMD + d1]
                  + w2 * bu[2 * DIMD + d1] + w3 * bu[3 * DIMD + d1];
#pragma unroll
        for (int reg = 0; reg < 4; ++reg) {
            int r0 = quad * 4 + reg;
            outw[(size_t)(r0) * DIMD + d0]      = c00[reg] + bb0;
            outw[(size_t)(r0) * DIMD + d1]      = c01[reg] + bb1;
            outw[(size_t)(r0 + 16) * DIMD + d0] = c10[reg] + bb0;
            outw[(size_t)(r0 + 16) * DIMD + d1] = c11[reg] + bb1;
        }
    }
}

// ---------------------------------------------------------------------------
extern "C" void kernel_launch(void* const* d_in, const int* in_sizes, int n_in,
                              void* d_out, int out_size, void* d_ws, size_t ws_size,
                              hipStream_t stream) {
    const float* x  = (const float*)d_in[0];
    const float* Wd = (const float*)d_in[1];
    const float* bd = (const float*)d_in[2];
    const float* Wu = (const float*)d_in[3];
    const float* bu = (const float*)d_in[4];
    const float* Wr = (const float*)d_in[5];
    const float* br = (const float*)d_in[6];
    float* out = (float*)d_out;

    char* ws = (char*)d_ws;
    float* poolP = (float*)(ws);               // 16 slots * 8 * 768 f32 = 393216 B
    short* WdP   = (short*)(ws + 393216);      // 147456 bf16 = 294912 B
    short* WuP   = (short*)(ws + 688128);      // 147456 bf16 = 294912 B (total 983040)

    hipMemsetAsync(poolP, 0, 393216, stream);
    prologue<<<2240, 192, 0, stream>>>(x, Wd, Wu, WdP, WuP, poolP);
    adapter_main<<<dim3(128, 8), 256, 0, stream>>>(x, bd, WdP, WuP, poolP, Wr, br, bu, out);
}